// Round 9
// baseline (1764.190 us; speedup 1.0000x reference)
//
#include <hip/hip_runtime.h>
#include <hip/hip_cooperative_groups.h>
#include <math.h>

namespace cg = cooperative_groups;

#define H_ 8
#define DH_ 64
#define DIM_ 512
#define M_ 256
#define N_ 8192
#define BH_ 16
#define LG_ 32
#define KC_ 33
#define CH_ 16   // a3 flash K-chunks
#define NTI_ 8   // 64-token tiles per chunk = N_/CH_/64

typedef __attribute__((ext_vector_type(8))) short bf16x8;
typedef __attribute__((ext_vector_type(4))) short s16x4;
typedef __attribute__((ext_vector_type(4))) float f32x4;

__device__ __forceinline__ short f2bf(float f) {
  unsigned u = __float_as_uint(f);
  unsigned r = (u + 0x7FFF + ((u >> 16) & 1)) >> 16;  // RNE
  return (short)r;
}
__device__ __forceinline__ float bf2f(short s) {
  return __uint_as_float(((unsigned)(unsigned short)s) << 16);
}

// =================== bf16 MFMA NT core (128x128 tile) ===================
__device__ __forceinline__ void mfma_nt_core(const short* __restrict__ A,
                                             const short* __restrict__ Bt, int K,
                                             int m0, int n0, size_t lda, size_t ldb,
                                             f32x4 acc[4][4], short* As, short* Bs) {
  const int tid = threadIdx.x;
  const int wave = tid >> 6, lane = tid & 63;
  const int wr = (wave >> 1) * 64, wc = (wave & 1) * 64;
  const int mi = lane & 15, quad = lane >> 4;
  for (int k0 = 0; k0 < K; k0 += 32) {
#pragma unroll
    for (int t = 0; t < 2; ++t) {
      const int cbase = (t * 4 + wave) * 64;
      const int chunk = cbase + lane;
      const int row = chunk >> 2, cc = (chunk & 3) * 8;
      __builtin_amdgcn_global_load_lds(
          (const __attribute__((address_space(1))) void*)(A + (size_t)(m0 + row) * lda + k0 + cc),
          (__attribute__((address_space(3))) void*)(As + (size_t)cbase * 8), 16, 0, 0);
      __builtin_amdgcn_global_load_lds(
          (const __attribute__((address_space(1))) void*)(Bt + (size_t)(n0 + row) * ldb + k0 + cc),
          (__attribute__((address_space(3))) void*)(Bs + (size_t)cbase * 8), 16, 0, 0);
    }
    __syncthreads();
    bf16x8 af[4], bf[4];
#pragma unroll
    for (int i = 0; i < 4; ++i)
      af[i] = *(const bf16x8*)&As[(wr + i * 16 + mi) * 32 + quad * 8];
#pragma unroll
    for (int j = 0; j < 4; ++j)
      bf[j] = *(const bf16x8*)&Bs[(wc + j * 16 + mi) * 32 + quad * 8];
#pragma unroll
    for (int i = 0; i < 4; ++i)
#pragma unroll
      for (int j = 0; j < 4; ++j)
        acc[i][j] = __builtin_amdgcn_mfma_f32_16x16x32_bf16(af[i], bf[j], acc[i][j], 0, 0, 0);
    __syncthreads();
  }
}

// QKV GEMM -> bf16 q/k/v (bh,n,d), q scaled
__global__ __launch_bounds__(256) void qkv_mfma(const short* __restrict__ xnb,
                                                const short* __restrict__ wt,
                                                short* __restrict__ qb, short* __restrict__ kb,
                                                short* __restrict__ vb) {
  __shared__ short As[128 * 32], Bs[128 * 32];
  f32x4 acc[4][4] = {};
  const int m0 = blockIdx.x * 128, n0 = blockIdx.y * 128;
  mfma_nt_core(xnb, wt, DIM_, m0, n0, DIM_, DIM_, acc, As, Bs);
  const int wave = threadIdx.x >> 6, lane = threadIdx.x & 63;
  const int wr = (wave >> 1) * 64, wc = (wave & 1) * 64;
  const int mi = lane & 15, quad = lane >> 4;
  const int which = n0 >> 9;
  short* dst = which == 0 ? qb : which == 1 ? kb : vb;
  const float sc = which == 0 ? 0.125f : 1.0f;
#pragma unroll
  for (int j = 0; j < 4; ++j) {
    const int col = n0 + wc + j * 16 + mi;
    const int h = (col >> 6) & 7, d = col & 63;
#pragma unroll
    for (int i = 0; i < 4; ++i) {
#pragma unroll
      for (int r = 0; r < 4; ++r) {
        const int row = m0 + wr + i * 16 + quad * 4 + r;
        const int b = row >> 13, t = row & (N_ - 1);
        dst[((size_t)(b * H_ + h) * N_ + t) * DH_ + d] = f2bf(acc[i][j][r] * sc);
      }
    }
  }
}

// final: y = x + omb @ woutt^T + b_out
__global__ __launch_bounds__(256) void final_mfma(const short* __restrict__ omb,
                                                  const short* __restrict__ wt,
                                                  const float* __restrict__ x,
                                                  const float* __restrict__ bout,
                                                  float* __restrict__ y) {
  __shared__ short As[128 * 32], Bs[128 * 32];
  f32x4 acc[4][4] = {};
  const int m0 = blockIdx.x * 128, n0 = blockIdx.y * 128;
  mfma_nt_core(omb, wt, DIM_, m0, n0, DIM_, DIM_, acc, As, Bs);
  const int wave = threadIdx.x >> 6, lane = threadIdx.x & 63;
  const int wr = (wave >> 1) * 64, wc = (wave & 1) * 64;
  const int mi = lane & 15, quad = lane >> 4;
#pragma unroll
  for (int j = 0; j < 4; ++j) {
    const int col = n0 + wc + j * 16 + mi;
    const float bo = bout[col];
#pragma unroll
    for (int i = 0; i < 4; ++i) {
#pragma unroll
      for (int r = 0; r < 4; ++r) {
        const int row = m0 + wr + i * 16 + quad * 4 + r;
        y[(size_t)row * DIM_ + col] = acc[i][j][r] + x[(size_t)row * DIM_ + col] + bo;
      }
    }
  }
}

// fp32 (K x N) -> bf16 transposed (N x K)
__global__ __launch_bounds__(256) void convt_kernel(const float* __restrict__ in,
                                                    short* __restrict__ out, int K, int N) {
  __shared__ float tile[32][33];
  const int n0 = blockIdx.x * 32, k0 = blockIdx.y * 32;
  const int tx = threadIdx.x & 31, ty = threadIdx.x >> 5;
  for (int r = ty; r < 32; r += 8) tile[r][tx] = in[(size_t)(k0 + r) * N + n0 + tx];
  __syncthreads();
  for (int r = ty; r < 32; r += 8) out[(size_t)(n0 + r) * K + k0 + tx] = f2bf(tile[tx][r]);
}

// bf16 v (bh,t,d) -> vtb (bh,d,t): 32x32 LDS tiles, conflict-free (+1 pad)
__global__ __launch_bounds__(256) void vt_kernel(const short* __restrict__ vb,
                                                 short* __restrict__ vtb) {
  __shared__ short tile[32][33];
  const int t0 = blockIdx.x * 32, d0 = blockIdx.y * 32, bh = blockIdx.z;
  const int tx = threadIdx.x & 31, ty = threadIdx.x >> 5;
  for (int r = ty; r < 32; r += 8)
    tile[r][tx] = vb[((size_t)bh * N_ + t0 + r) * DH_ + d0 + tx];
  __syncthreads();
  for (int r = ty; r < 32; r += 8)
    vtb[((size_t)bh * DH_ + d0 + r) * N_ + t0 + tx] = tile[tx][r];
}

// ---------------- LayerNorm -> bf16 (wave-per-row, shfl reduce, no LDS) ----------------
__global__ __launch_bounds__(256) void ln_kernel(const float* __restrict__ x,
                                                 const float* __restrict__ gamma,
                                                 const float* __restrict__ beta,
                                                 short* __restrict__ xnb) {
  const int row = blockIdx.x * 4 + (threadIdx.x >> 6);
  const int lane = threadIdx.x & 63;
  const float4* xr = (const float4*)(x + (size_t)row * DIM_) + lane * 2;
  const float4 v0 = xr[0], v1 = xr[1];
  float s = v0.x + v0.y + v0.z + v0.w + v1.x + v1.y + v1.z + v1.w;
  float ss = v0.x * v0.x + v0.y * v0.y + v0.z * v0.z + v0.w * v0.w +
             v1.x * v1.x + v1.y * v1.y + v1.z * v1.z + v1.w * v1.w;
#pragma unroll
  for (int off = 1; off < 64; off <<= 1) {
    s += __shfl_xor(s, off, 64);
    ss += __shfl_xor(ss, off, 64);
  }
  const float mu = s * (1.0f / DIM_);
  const float var = ss * (1.0f / DIM_) - mu * mu;
  const float rs = rsqrtf(var + 1e-5f);
  const float4 g0 = ((const float4*)gamma)[lane * 2], g1 = ((const float4*)gamma)[lane * 2 + 1];
  const float4 b0 = ((const float4*)beta)[lane * 2], b1 = ((const float4*)beta)[lane * 2 + 1];
  bf16x8 o;
  o[0] = f2bf((v0.x - mu) * rs * g0.x + b0.x);
  o[1] = f2bf((v0.y - mu) * rs * g0.y + b0.y);
  o[2] = f2bf((v0.z - mu) * rs * g0.z + b0.z);
  o[3] = f2bf((v0.w - mu) * rs * g0.w + b0.w);
  o[4] = f2bf((v1.x - mu) * rs * g1.x + b1.x);
  o[5] = f2bf((v1.y - mu) * rs * g1.y + b1.y);
  o[6] = f2bf((v1.z - mu) * rs * g1.z + b1.z);
  o[7] = f2bf((v1.w - mu) * rs * g1.w + b1.w);
  *(bf16x8*)(xnb + (size_t)row * DIM_ + lane * 8) = o;
}

// ---------------- landmarks ----------------
__global__ __launch_bounds__(256) void landmark_kernel(const short* __restrict__ qb,
                                                       const short* __restrict__ kb,
                                                       float* __restrict__ ql,
                                                       float* __restrict__ kl,
                                                       short* __restrict__ qlb,
                                                       short* __restrict__ klb) {
  const int idx = blockIdx.x * 256 + threadIdx.x;
  const int d = idx & (DH_ - 1);
  const int m = (idx >> 6) & (M_ - 1);
  const int bh = idx >> 14;
  const size_t base = ((size_t)bh * N_ + m * LG_) * DH_ + d;
  float sq = 0.f, sk = 0.f;
#pragma unroll 8
  for (int t = 0; t < LG_; ++t) {
    sq += bf2f(qb[base + (size_t)t * DH_]);
    sk += bf2f(kb[base + (size_t)t * DH_]);
  }
  sq *= (1.0f / LG_);
  sk *= (1.0f / LG_);
  ql[idx] = sq;
  kl[idx] = sk;
  qlb[idx] = f2bf(sq);
  klb[idx] = f2bf(sk);
}

// ---------------- sim2 + softmax ----------------
__global__ __launch_bounds__(256) void sim2_softmax(const float* __restrict__ ql,
                                                    const float* __restrict__ kl,
                                                    float* __restrict__ a2,
                                                    short* __restrict__ a2b) {
  const int i = blockIdx.x, bh = blockIdx.y, j = threadIdx.x;
  __shared__ float qrow[DH_];
  if (j < DH_) qrow[j] = ql[((size_t)bh * M_ + i) * DH_ + j];
  __syncthreads();
  const float* kr = kl + ((size_t)bh * M_ + j) * DH_;
  float s = 0.f;
#pragma unroll 16
  for (int d = 0; d < DH_; ++d) s += qrow[d] * kr[d];
  __shared__ float red[256];
  red[j] = s;
  __syncthreads();
  for (int off = 128; off > 0; off >>= 1) {
    if (j < off) red[j] = fmaxf(red[j], red[j + off]);
    __syncthreads();
  }
  const float mx = red[0];
  __syncthreads();
  const float e = expf(s - mx);
  red[j] = e;
  __syncthreads();
  for (int off = 128; off > 0; off >>= 1) {
    if (j < off) red[j] += red[j + off];
    __syncthreads();
  }
  const float out = e / red[0];
  a2[((size_t)bh * M_ + i) * M_ + j] = out;
  a2b[((size_t)bh * M_ + i) * M_ + j] = f2bf(out);
}

__global__ __launch_bounds__(256) void colmax_kernel(const float* __restrict__ a2,
                                                     unsigned int* __restrict__ scalebits) {
  const int bh = blockIdx.x, j = threadIdx.x;
  const float* mat = a2 + (size_t)bh * M_ * M_;
  float s = 0.f;
  for (int i = 0; i < M_; ++i) s += fabsf(mat[i * M_ + j]);
  __shared__ float red[256];
  red[j] = s;
  __syncthreads();
  for (int off = 128; off > 0; off >>= 1) {
    if (j < off) red[j] = fmaxf(red[j], red[j + off]);
    __syncthreads();
  }
  if (j == 0) atomicMax(scalebits, __float_as_uint(red[0]));
}

// z0b = bf16(a2^T / scale)
__global__ __launch_bounds__(256) void transpose_scale(const float* __restrict__ a2,
                                                       short* __restrict__ z0b,
                                                       const unsigned int* __restrict__ scalebits) {
  const float inv = 1.0f / __uint_as_float(*scalebits);
  const int idx = blockIdx.x * 256 + threadIdx.x;
  const int j = idx & (M_ - 1), i = (idx >> 8) & (M_ - 1), bh = idx >> 16;
  z0b[idx] = f2bf(a2[((size_t)bh * M_ + j) * M_ + i] * inv);
}

// ============ Newton-Schulz bf16 MFMA machinery (64x64 tiles of 256^2, K=256) ============
// ONE barrier per GEMM. A-frags direct from global into af[8] regs (lane-private
// rows). B reg-staged in one shot then LDS stride-260. LDS 33,280 B.
__device__ __forceinline__ void ns_core(const short* __restrict__ A, const short* __restrict__ B,
                                        int m0, int n0, short* Bs, f32x4 acc[4]) {
  const int tid = threadIdx.x, wave = tid >> 6, lane = tid & 63;
  const int mi = lane & 15, quad = lane >> 4;
  const int bkk = tid & 31, g = tid >> 5;
  bf16x8 bv[8];
#pragma unroll
  for (int kc = 0; kc < 8; ++kc)
    bv[kc] = *(const bf16x8*)(B + (size_t)(kc * 32 + bkk) * M_ + n0 + g * 8);
  const short* arow = A + (size_t)(m0 + wave * 16 + mi) * M_;
  bf16x8 af[8];
#pragma unroll
  for (int k0 = 0; k0 < 8; ++k0)
    af[k0] = *(const bf16x8*)(arow + k0 * 32 + quad * 8);
#pragma unroll
  for (int kc = 0; kc < 8; ++kc)
#pragma unroll
    for (int e = 0; e < 8; ++e)
      Bs[(g * 8 + e) * 260 + kc * 32 + bkk] = bv[kc][e];
  __syncthreads();
#pragma unroll
  for (int k0 = 0; k0 < 8; ++k0) {
#pragma unroll
    for (int j = 0; j < 4; ++j) {
      union { bf16x8 v; s16x4 h[2]; } bfr;
      const short* bp = &Bs[(j * 16 + mi) * 260 + k0 * 32 + quad * 8];
      bfr.h[0] = *(const s16x4*)bp;
      bfr.h[1] = *(const s16x4*)(bp + 4);
      acc[j] = __builtin_amdgcn_mfma_f32_16x16x32_bf16(af[k0], bfr.v, acc[j], 0, 0, 0);
    }
  }
}

// bijective XCD spread for n work units (n % 8 == 0)
__device__ __forceinline__ int ns_swz(int bid, int n) {
  return (bid & 7) * (n >> 3) + (bid >> 3);
}

// ---------------- fused Newton-Schulz: gemm0 + 6 x (stageA, stageB) ----------------
// ONE cooperative dispatch (512 blocks, all co-resident: LDS 33,280 B -> 4
// blocks/CU >= the 2/CU needed). grid.sync() replaces 12 kernel boundaries.
// Buffer ping-pong by iteration parity. __threadfence() before each sync for
// device-scope visibility across XCDs (G16).
__global__ __launch_bounds__(256) void ns_fused(const short* __restrict__ a2b,
                                                short* __restrict__ zb0, short* __restrict__ zb1,
                                                short* __restrict__ yb0, short* __restrict__ yb1,
                                                short* __restrict__ p1b, short* __restrict__ y2b,
                                                short* __restrict__ wb,
                                                float* __restrict__ z0f) {
  cg::grid_group grid = cg::this_grid();
  __shared__ short Bs[64 * 260];
  const int bid = blockIdx.x;
  const int wave = threadIdx.x >> 6, lane = threadIdx.x & 63;
  const int mi = lane & 15, quad = lane >> 4;

  // ---- gemm0: y0 = a2b @ z0 (256 work units on blocks 0..255) ----
  if (bid < 256) {
    const int w = ns_swz(bid, 256);
    const int bx = w & 15, bh = w >> 4;
    const int m0 = (bx >> 2) * 64, n0 = (bx & 3) * 64;
    const size_t mo = (size_t)bh * (M_ * M_);
    f32x4 acc[4] = {};
    ns_core(a2b + mo, zb0 + mo, m0, n0, Bs, acc);
#pragma unroll
    for (int j = 0; j < 4; ++j)
#pragma unroll
      for (int r = 0; r < 4; ++r) {
        const int row = m0 + wave * 16 + quad * 4 + r, col = n0 + j * 16 + mi;
        yb0[mo + (size_t)row * M_ + col] = f2bf(acc[j][r]);
      }
  }
  __threadfence();
  grid.sync();

  for (int it = 0; it < 6; ++it) {
    const short* zc = (it & 1) ? zb1 : zb0;
    const short* yc = (it & 1) ? yb1 : yb0;
    short* zn = (it & 1) ? zb0 : zb1;
    const int last = (it == 5);

    // ---- stage A: sel0: p1 = z@y ; sel1: y2 = y@y, w = 1.75y - 0.25y2 ----
    {
      const int w = ns_swz(bid, 512);
      const int bx = w & 15, by = w >> 4;
      const int m0 = (bx >> 2) * 64, n0 = (bx & 3) * 64;
      const int sel = by & 1;
      const size_t mo = (size_t)(by >> 1) * (M_ * M_);
      f32x4 acc[4] = {};
      ns_core((sel ? yc : zc) + mo, yc + mo, m0, n0, Bs, acc);
#pragma unroll
      for (int j = 0; j < 4; ++j)
#pragma unroll
        for (int r = 0; r < 4; ++r) {
          const int row = m0 + wave * 16 + quad * 4 + r, col = n0 + j * 16 + mi;
          const size_t idx = mo + (size_t)row * M_ + col;
          if (sel) {
            y2b[idx] = f2bf(acc[j][r]);
            wb[idx] = f2bf(1.75f * bf2f(yc[idx]) - 0.25f * acc[j][r]);
          } else {
            p1b[idx] = f2bf(acc[j][r]);
          }
        }
    }
    __threadfence();
    grid.sync();

    // ---- stage B: sel0: zo = 3.25z - 3.75p1 + p1@w ; sel1: yo = 3.25y - 3.75y2 + y2@w ----
    if (!last) {
      short* yn = (it & 1) ? yb0 : yb1;
      const int w = ns_swz(bid, 512);
      const int bx = w & 15, by = w >> 4;
      const int m0 = (bx >> 2) * 64, n0 = (bx & 3) * 64;
      const int sel = by & 1;
      const size_t mo = (size_t)(by >> 1) * (M_ * M_);
      f32x4 acc[4] = {};
      ns_core((sel ? y2b : p1b) + mo, wb + mo, m0, n0, Bs, acc);
#pragma unroll
      for (int j = 0; j < 4; ++j)
#pragma unroll
        for (int r = 0; r < 4; ++r) {
          const int row = m0 + wave * 16 + quad * 4 + r, col = n0 + j * 16 + mi;
          const size_t idx = mo + (size_t)row * M_ + col;
          if (sel) {
            yn[idx] = f2bf(3.25f * bf2f(yc[idx]) - 3.75f * bf2f(y2b[idx]) + acc[j][r]);
          } else {
            zn[idx] = f2bf(3.25f * bf2f(zc[idx]) - 3.75f * bf2f(p1b[idx]) + acc[j][r]);
          }
        }
      __threadfence();
      grid.sync();
    } else if (bid < 256) {
      // zonly: 256 work units, fp32 z out
      const int w = ns_swz(bid, 256);
      const int bx = w & 15, bh = w >> 4;
      const int m0 = (bx >> 2) * 64, n0 = (bx & 3) * 64;
      const size_t mo = (size_t)bh * (M_ * M_);
      f32x4 acc[4] = {};
      ns_core(p1b + mo, wb + mo, m0, n0, Bs, acc);
#pragma unroll
      for (int j = 0; j < 4; ++j)
#pragma unroll
        for (int r = 0; r < 4; ++r) {
          const int row = m0 + wave * 16 + quad * 4 + r, col = n0 + j * 16 + mi;
          const size_t idx = mo + (size_t)row * M_ + col;
          const float v = 3.25f * bf2f(zc[idx]) - 3.75f * bf2f(p1b[idx]) + acc[j][r];
          z0f[idx] = v;
        }
    }
  }
}

// ---------------- fp32 64x64 core (w2 = z @ a3v, writes bf16 TRANSPOSED) ----------------
__device__ __forceinline__ void mm_step(float (*As)[68], float (*Bs)[68],
                                        int tr, int tc, float acc[4][4]) {
#pragma unroll
  for (int kk = 0; kk < 16; ++kk) {
    const float4 a4 = *(const float4*)&As[kk][tr * 4];
    const float4 b4 = *(const float4*)&Bs[kk][tc * 4];
    const float a[4] = {a4.x, a4.y, a4.z, a4.w};
    const float b[4] = {b4.x, b4.y, b4.z, b4.w};
#pragma unroll
    for (int i = 0; i < 4; ++i)
#pragma unroll
      for (int j = 0; j < 4; ++j) acc[i][j] = fmaf(a[i], b[j], acc[i][j]);
  }
}

__device__ __forceinline__ void load_a_tile(const float* A, int lda, int m0, int k0,
                                            int tid, float (*As)[68]) {
  const int r = tid >> 2, kq = tid & 3;
  const float4 a4 = *(const float4*)(A + (size_t)(m0 + r) * lda + k0 + kq * 4);
  As[kq * 4 + 0][r] = a4.x;
  As[kq * 4 + 1][r] = a4.y;
  As[kq * 4 + 2][r] = a4.z;
  As[kq * 4 + 3][r] = a4.w;
}

__device__ __forceinline__ void load_b_nn(const float* B, int ldb, int k0, int n0,
                                          int tid, float (*Bs)[68]) {
  const int kr = tid >> 4, c4 = tid & 15;
  const float4 b4 = *(const float4*)(B + (size_t)(k0 + kr) * ldb + n0 + c4 * 4);
  *(float4*)&Bs[kr][c4 * 4] = b4;
}

// w2tb[bh][d][M] = (z0f[bh] @ a3v[bh])^T in bf16 (w2t fused into epilogue)
__global__ __launch_bounds__(256) void gemm_nn64(const float* __restrict__ A, int lda,
                                                 long long strideA,
                                                 const float* __restrict__ B, long long strideB,
                                                 short* __restrict__ w2tb, int kchunk) {
  const int bz = blockIdx.z;
  A += (size_t)bz * strideA;
  B += (size_t)bz * strideB;
  const int m0 = blockIdx.x * 64;
  const int tid = threadIdx.x, tr = tid >> 4, tc = tid & 15;
  __shared__ float As[16][68], Bs[16][68];
  float acc[4][4] = {};
  for (int k0 = 0; k0 < kchunk; k0 += 16) {
    load_a_tile(A, lda, m0, k0, tid, As);
    load_b_nn(B, DH_, k0, 0, tid, Bs);
    __syncthreads();
    mm_step(As, Bs, tr, tc, acc);
    __syncthreads();
  }
#pragma unroll
  for (int i = 0; i < 4; ++i) {
    const int row = m0 + tr * 4 + i;
#pragma unroll
    for (int j = 0; j < 4; ++j)
      w2tb[((size_t)bz * DH_ + tc * 4 + j) * M_ + row] = f2bf(acc[i][j]);
  }
}

// ---------------- a3 flash (double-buffered ks + staged vs, 1 barrier/iter) ----------------
__device__ __forceinline__ void stage_ks(const short* __restrict__ kb, int bh, int n0,
                                         int wave, int lane, short* ks) {
#pragma unroll
  for (int i = 0; i < 2; ++i) {
    const int cb = i * 256 + wave * 64;
    const int c = cb + lane;
    const int row = c >> 3, cc = c & 7;
    __builtin_amdgcn_global_load_lds(
        (const __attribute__((address_space(1))) void*)(
            kb + ((size_t)bh * N_ + n0 + row) * DH_ + ((cc ^ (row & 7)) * 8)),
        (__attribute__((address_space(3))) void*)(ks + (size_t)cb * 8), 16, 0, 0);
  }
}

__device__ __forceinline__ void stage_vs(const short* __restrict__ vtb, int bh, int n0,
                                         int wave, int lane, short* vs) {
#pragma unroll
  for (int i = 0; i < 2; ++i) {
    const int cb = i * 256 + wave * 64;
    const int c = cb + lane;
    const int row = c >> 3, cc = c & 7;  // row = d index
    __builtin_amdgcn_global_load_lds(
        (const __attribute__((address_space(1))) void*)(
            vtb + ((size_t)bh * DH_ + row) * N_ + n0 + ((cc ^ (row & 7)) * 8)),
        (__attribute__((address_space(3))) void*)(vs + (size_t)cb * 8), 16, 0, 0);
  }
}

__global__ __launch_bounds__(256) void a3_flash(const short* __restrict__ qlb,
                                                const short* __restrict__ kb,
                                                const short* __restrict__ vtb,
                                                float* __restrict__ Opart,
                                                float* __restrict__ mpart,
                                                float* __restrict__ lpart) {
  const int chunk = blockIdx.x, rt = blockIdx.y, bh = blockIdx.z;
  __shared__ short ks[2][64 * 64];
  __shared__ short vs[2][64 * 64];
  __shared__ short ps[64 * 64];
  const int tid = threadIdx.x, wave = tid >> 6, lane = tid & 63;
  const int mi = lane & 15, quad = lane >> 4;
  // q frags direct from global (lane-private rows)
  const short* qrow = qlb + ((size_t)bh * M_ + rt * 64 + wave * 16 + mi) * DH_;
  const bf16x8 aq0 = *(const bf16x8*)(qrow + quad * 8);
  const bf16x8 aq1 = *(const bf16x8*)(qrow + 32 + quad * 8);
  float m[4] = {-INFINITY, -INFINITY, -INFINITY, -INFINITY};
  float l[4] = {0.f, 0.f, 0.f, 0.f};  // per-lane PARTIAL sums (reduced at epilogue)
  f32x4 o[4] = {};
  const int nbase = chunk * (N_ / CH_);
  stage_ks(kb, bh, nbase, wave, lane, ks[0]);
  stage_vs(vtb, bh, nbase, wave, lane, vs[0]);
  __syncthreads();  // vmcnt drained -> buf0 ready
  for (int t = 0; t < NTI_; ++t) {
    const int cur = t & 1;
    if (t + 1 < NTI_) {
      stage_ks(kb, bh, nbase + (t + 1) * 64, wave, lane, ks[cur ^ 1]);
      stage_vs(vtb, bh, nbase + (t + 1) * 64, wave, lane, vs[cur ^ 1]);
    }
    f32x4 s[4];
#pragma unroll
    for (int j = 0; j < 4; ++j) {
      const int row = j * 16 + mi;
      const bf16x8 b0 = *(const bf16x8*)&ks[cur][row * 64 + ((quad ^ (row & 7)) * 8)];
      const bf16x8 b1 = *(const bf16x8*)&ks[cur][row * 64 + (((quad + 4) ^ (row & 7)) * 8)];
      f32x4 z = {0.f, 0.f, 0.f, 0.f};
      z = __builtin_amdgcn_mfma_f32_16x16x32_bf16(aq0, b0, z, 0, 0, 0);
      s[j] = __builtin_amdgcn_mfma_f32_16x16x32_bf16(aq1, b1, z, 0, 0, 0);
    }
    float alpha[4];
#pragma unroll
    for (int r = 0; r < 4; ++r) {
      float v = fmaxf(fmaxf(s[0][r], s[1][r]), fmaxf(s[2][r], s[3][r]));
      v = fmaxf(v, __shfl_xor(v, 1, 64));
      v = fmaxf(v, __shfl_xor(v, 2, 64));
      v = fmaxf(v, __shfl_xor(v, 4, 64));
      v = fmaxf(v, __shfl_xor(v, 8, 64));
      const float mnew = fmaxf(m[r], v);
      alpha[r] = __expf(m[r] - mnew);
      m[r] = mnew;
    }
    float rs[4] = {0.f, 0.f, 0.f, 0.f};
#pragma unroll
    for (int j = 0; j < 4; ++j)
#pragma unroll
      for (int r = 0; r < 4; ++r) {
        const float p = __expf(s[j][r] - m[r]);
        rs[r] += p;
        const int prow = wave * 16 + quad * 4 + r;
        const int pcol = j * 16 + mi;
        ps[prow * 64 + (((pcol >> 3) ^ (prow & 7)) * 8) + (pcol & 7)] = f2bf(p);
      }
#pragma unroll
    for (int r = 0; r < 4; ++r) {
      l[r] = l[r] * alpha[r] + rs[r];  // per-lane partial (alpha row-uniform)
#pragma unroll
      for (int j = 0; j < 4; ++j) o[j][r] *= alpha[r];
    }
    // ps row stripe wave-private: in-order DS pipe orders write->read
    const int prow = wave * 16 + mi;
    const bf16x8 ap0 = *(const bf16x8*)&ps[prow * 64 + ((quad ^ (mi & 7)) * 8)];
    const bf16x8 ap1 = *(const bf16x8*)&ps[prow * 64 + (((quad + 4) ^ (mi & 7)) * 8)];
#pragma unroll
    for (int j = 0; j < 4; ++j) {
      const int vrow = j * 16 + mi;
      const bf16x8 b0 = *(const bf16x8*)&vs[cur][vrow * 64 + ((quad ^ (vrow & 7)) * 8)];
      const bf16x8 b1 = *(const bf16x8*)&vs[cur][vrow * 64 + (((quad + 4) ^ (vrow & 7)) * 8)];
      o[j] = __builtin_amdgcn_mfma_f32_16x16x32_bf16(ap0, b0, o[j], 0, 0, 0);
      o[j] = __builtin_amdgcn_mfma_f32_16x16x32_bf16(ap1, b1, o[j], 0, 0, 0);
    }
    __syncthreads();  // single barrier: drains next-tile vmcnt + closes WAR on cur
  }
#pragma unroll
  for (int r = 0; r < 4; ++r) {
    float v = l[r];
    v += __shfl_xor(v, 1, 64);
    v += __shfl_xor(v, 2, 64);
    v += __shfl_xor(v, 4, 64);
    v += __shfl_xor(v, 8, 64);
    l[r] = v;
  }
  const int p2 = bh * 4 + rt;
  float* Ob = Opart + ((size_t)chunk * 64 + p2) * 4096;
#pragma unroll
  for (int j = 0; j < 4; ++j)
#pragma unroll
    for (int r = 0; r < 4; ++r)
      Ob[(wave * 16 + quad * 4 + r) * 64 + j * 16 + mi] = o[j][r];
  if (mi == 0) {
#pragma unroll
    for (int r = 0; r < 4; ++r) {
      mpart[((size_t)chunk * 64 + p2) * 64 + wave * 16 + quad * 4 + r] = m[r];
      lpart[((size_t)chunk * 64 + p2) * 64 + wave * 16 + quad * 4 + r] = l[r];
    }
  }
}

// grid (64, 4): each block combines one p2 over a quarter of the 64x64 output
__global__ __launch_bounds__(256) void a3_combine(const float* __restrict__ Opart,
                                                  const float* __restrict__ mpart,
                                                  const float* __restrict__ lpart,
                                                  float* __restrict__ a3v) {
  const int p2 = blockIdx.x, ds = blockIdx.y;
  const int bh = p2 >> 2, rt = p2 & 3;
  __shared__ float wgt[CH_][64];
  const int tid = threadIdx.x;
  if (tid < 64) {
    float mg = -INFINITY;
#pragma unroll
    for (int c = 0; c < CH_; ++c) mg = fmaxf(mg, mpart[((size_t)c * 64 + p2) * 64 + tid]);
    float e[CH_], lg = 0.f;
#pragma unroll
    for (int c = 0; c < CH_; ++c) {
      e[c] = __expf(mpart[((size_t)c * 64 + p2) * 64 + tid] - mg);
      lg += lpart[((size_t)c * 64 + p2) * 64 + tid] * e[c];
    }
    const float inv = 1.f / lg;
#pragma unroll
    for (int c = 0; c < CH_; ++c) wgt[c][tid] = e[c] * inv;
  }
  __syncthreads();
  for (int i = ds * 1024 + tid; i < ds * 1024 + 1024; i += 256) {
    const int row = i >> 6, d = i & 63;
    float s = 0.f;
#pragma unroll
    for (int c = 0; c < CH_; ++c) s += Opart[((size_t)c * 64 + p2) * 4096 + i] * wgt[c][row];
    a3v[((size_t)bh * M_ + rt * 64 + row) * DH_ + d] = s;
  }
}

// ---------------- a1 fused: omb = softmax(q @ kl^T) @ w2 + Band@Vwin (conv) ----------------
// Measured-best (R6): single staging of ALL 256 landmarks (8 gload_lds in
// flight, one wait), T14 vwin (global loads to regs at kernel start, LDS write
// after post-QK barrier into a region disjoint from ps), deferred
// sum-normalization. 3 barriers total. LDS layout (34,944 B, 4 blocks/CU):
//   kls [0,32768)  = [256][64] staged          (dead after QK)
//   ps  [0,17920)  = [64][140]  aliases kls    (wave-private stripes)
//   vwin[17920,32768) = [64][116] aliases kls  (disjoint from ps!)
//   band[32768,34944) = [16][68]
__global__ __launch_bounds__(256, 4) void a1_conv(const short* __restrict__ qb,
                                                  const short* __restrict__ klb,
                                                  const short* __restrict__ w2tb,
                                                  const short* __restrict__ vtb,
                                                  const float* __restrict__ rk,
                                                  short* __restrict__ omb) {
  __shared__ __align__(16) char smem[34944];
  short* kls = (short*)smem;
  short* ps = (short*)smem;
  short* vwin = (short*)(smem + 17920);
  short* band = (short*)(smem + 32768);
  const int bh = blockIdx.y, t0 = blockIdx.x * 64;
  const int b = bh >> 3, h = bh & 7;
  const int tid = threadIdx.x, wave = tid >> 6, lane = tid & 63;
  const int mi = lane & 15, quad = lane >> 4;

  // q A-frags direct from global (wave-private rows, no reuse)
  const short* qrow = qb + ((size_t)bh * N_ + t0 + wave * 16 + mi) * DH_;
  const bf16x8 aq0 = *(const bf16x8*)(qrow + quad * 8);
  const bf16x8 aq1 = *(const bf16x8*)(qrow + 32 + quad * 8);

  // T14 vwin: issue global loads into REGISTERS now; LDS write happens after
  // the post-QK barrier -> HBM latency hides under staging+QK+softmax.
  const int vd = tid & 63, cg0 = tid >> 6;
  bf16x8 vreg[4];
  {
    const short* vrow = vtb + ((size_t)bh * DH_ + vd) * N_;
#pragma unroll
    for (int slot = 0; slot < 4; ++slot) {
      const int ch = cg0 + slot * 4;
      bf16x8 vv = {};
      if (ch < 14) {
        const int tbase = t0 - 16 + ch * 8;
        if (tbase >= 0 && tbase + 8 <= N_) {
          vv = *(const bf16x8*)(vrow + tbase);
        } else {
#pragma unroll
          for (int e = 0; e < 8; ++e) {
            const int tt = tbase + e;
            vv[e] = (tt >= 0 && tt < N_) ? vrow[tt] : (short)0;
          }
        }
      }
      vreg[slot] = vv;
    }
  }
  // band build (disjoint region, covered by bar1)
#pragma unroll
  for (int i = 0; i < 4; ++i) {
    const int idx = tid + i * 256;  // < 1024
    const int r = idx >> 6, c = idx & 63, u = c - r;
    band[r * 68 + c] = (u >= 0 && u < KC_) ? f2bf(rk[h * KC_ + u]) : (short)0;
  }

  // stage ALL 256 landmark rows (8 gload_lds/thread, source-side XOR swizzle)
#pragma unroll
  for (int i = 0; i < 8; ++i) {
    const int cb = i * 256 + wave * 64;  // wave-uniform chunk base
    const int c = cb + lane;
    const int row = c >> 3, cc = c & 7;
    __builtin_amdgcn_global_load_lds(
        (const __attribute__((address_space(1))) void*)(
            klb + ((size_t)bh * M_ + row) * DH_ + (cc ^ (row & 7)) * 8),
        (__attribute__((address_space(3))) void*)(kls + (size_t)cb * 8), 16, 0, 0);
  }
  __syncthreads();  // bar1: staging (and band) complete

  // QK over all 256 landmarks
  f32x4 s[16] = {};
#pragma unroll
  for (int f = 0; f < 16; ++f) {
    const int row = f * 16 + mi;
    const bf16x8 blo = *(const bf16x8*)&kls[row * 64 + ((quad ^ (row & 7)) * 8)];
    const bf16x8 bhi = *(const bf16x8*)&kls[row * 64 + (((quad + 4) ^ (row & 7)) * 8)];
    f32x4 z = __builtin_amdgcn_mfma_f32_16x16x32_bf16(aq0, blo, s[f], 0, 0, 0);
    s[f] = __builtin_amdgcn_mfma_f32_16x16x32_bf16(aq1, bhi, z, 0, 0, 0);
  }
  // exact softmax: max reduce + exp; sum kept as per-lane partial (deferred)
  float lsum[4];
#pragma unroll
  for (int r = 0; r < 4; ++r) {
    float v = s[0][r];
#pragma unroll
    for (int f = 1; f < 16; ++f) v = fmaxf(v, s[f][r]);
    v = fmaxf(v, __shfl_xor(v, 1, 64));
    v = fmaxf(v, __shfl_xor(v, 2, 64));
    v = fmaxf(v, __shfl_xor(v, 4, 64));
    v = fmaxf(v, __shfl_xor(v, 8, 64));
    float sum = 0.f;
#pragma unroll
    for (int f = 0; f < 16; ++f) {
      const float p = __expf(s[f][r] - v);
      s[f][r] = p;
      sum += p;
    }
    lsum[r] = sum;
  }
  __syncthreads();  // bar2: kls reads done by ALL waves; ps+vwin regions free

  // vwin LDS write from prefetched registers (region disjoint from ps)
#pragma unroll
  for (int slot = 0; slot < 4; ++slot) {
    const int ch = cg0 + slot * 4;
    if (ch < 14) *(bf16x8*)&vwin[vd * 116 + ch * 8] = vreg[slot];
  }

  // PV in two halves with UNNORMALIZED p (wave-private ps stripes, no barriers)
  f32x4 o[4] = {};
#pragma unroll
  for (int half = 0; half < 2; ++half) {
#pragma unroll
    for (int f = 0; f < 8; ++f)
#pragma unroll
      for (int r = 0; r < 4; ++r)
        ps[(wave * 16 + quad * 4 + r) * 140 + f * 16 + mi] = f2bf(s[half * 8 + f][r]);
#pragma unroll
    for (int k0 = 0; k0 < 4; ++k0) {
      union { bf16x8 v; s16x4 hh[2]; } ap;
      const short* pp = &ps[(wave * 16 + mi) * 140 + k0 * 32 + quad * 8];
      ap.hh[0] = *(const s16x4*)pp;
      ap.hh[1] = *(const s16x4*)(pp + 4);
#pragma unroll
      for (int j = 0; j < 4; ++j) {
        const bf16x8 bw = *(const bf16x8*)(w2tb + ((size_t)bh * DH_ + j * 16 + mi) * M_ +
                                           (half * 4 + k0) * 32 + quad * 8);
        o[j] = __builtin_amdgcn_mfma_f32_16x16x32_bf16(ap.v, bw, o[j], 0, 0, 0);
      }
    }
  }
  // deferred sum reduce + normalization (before conv add)
#pragma unroll
  for (int r = 0; r < 4; ++r) {
    float v = lsum[r];
    v += __shfl_xor(v, 1, 64);
    v += __shfl_xor(v, 2, 64);
    v += __shfl_xor(v, 4, 64);
    v += __shfl_xor(v, 8, 64);
    const float inv = 1.f / v;
#pragma unroll
    for (int j = 0; j < 4; ++j) o[j][r] *= inv;
  }
  __syncthreads();  // bar3: vwin writes visible to all waves

  // conv: o += Band(16x64) @ Vwin-slice (wave-offset window)
#pragma unroll
  for (int ks = 0; ks < 2; ++ks) {
    union { bf16x8 v; s16x4 hh[2]; } ab;
    const short* bp = &band[mi * 68 + ks * 32 + quad * 8];
    ab.hh[0] = *(const s16x4*)bp;
    ab.hh[1] = *(const s16x4*)(bp + 4);
#pragma unroll
    for (int j = 0; j < 4; ++j) {
      union { bf16x8 v; s16x4 hh[2]; } bv;
      const short* vp = &vwin[(j * 16 + mi) * 116 + wave * 16 + ks * 32 + quad * 8];
      bv.hh[0] = *(const s16x4*)vp;
      bv.hh[1] = *(const s16x4*)(vp + 4);
      o[j] = __builtin_amdgcn_mfma_f32_16x16x32_bf16(ab.v, bv.v, o[j], 0, 0, 0);
    }
  }
  // epilogue
#pragma unroll
  for (int j = 0; j < 4; ++j) {
    const int d = j * 16 + mi;
#pragma unroll
    for (int r = 0; r < 4; ++r) {
      const int t = t0 + wave * 16 + quad * 4 + r;
      omb[((size_t)(b * N_ + t)) * DIM_ + h * DH_ + d] = f2bf(o[j][r]);
    }
  }
}

extern "C" void kernel_launch(void* const* d_in, const int* in_sizes, int n_in,
                              void* d_out, int out_size, void* d_ws, size_t ws_size,
                              hipStream_t stream) {
  (void)in_sizes; (void)n_in; (void)out_size;
  const float* x = (const float*)d_in[0];
  const float* gamma = (const float*)d_in[1];
  const float* beta = (const float*)d_in[2];
  const float* wqkv = (const float*)d_in[3];
  const float* wout = (const float*)d_in[4];
  const float* bout = (const float*)d_in[5];
  const float* rk = (const float*)d_in[6];
  float* y = (float*)d_out;
  float* ws = (float*)d_ws;

  size_t o = 0;
  short* xnb = (short*)(ws + o);   o += (size_t)2 * N_ * DIM_ / 2;
  short* wqkvt = (short*)(ws + o); o += (size_t)3 * DIM_ * DIM_ / 2;
  short* woutt = (short*)(ws + o); o += (size_t)DIM_ * DIM_ / 2;
  short* qb = (short*)(ws + o);    o += (size_t)BH_ * N_ * DH_ / 2;
  short* kb = (short*)(ws + o);    o += (size_t)BH_ * N_ * DH_ / 2;
  short* vb = (short*)(ws + o);    o += (size_t)BH_ * N_ * DH_ / 2;
  short* vtb = (short*)(ws + o);   o += (size_t)BH_ * N_ * DH_ / 2;
  float* ql = ws + o;  o += (size_t)BH_ * M_ * DH_;
  float* kl = ws + o;  o += (size_t)BH_ * M_ * DH_;
  short* qlb = (short*)(ws + o); o += (size_t)BH_ * M_ * DH_ / 2;
  short* klb = (short*)(ws + o); o += (size_t)BH_ * M_ * DH_ / 2;
  float* a2 = ws + o;  o += (size_t)BH_ * M_ * M_;
  float* z0f = ws + o; o += (size_t)BH_ * M_ * M_;
  short* a2b = (short*)(ws + o); o += (size_t)BH_ * M_ * M_ / 2;
  short* zb0 = (short*)(ws + o); o += (size_t)BH_ * M_ * M_ / 2;
  short* zb1 = (short*)(ws + o); o += (size_t)BH_ * M_ * M_ / 2;
  short* yb0 = (short*)(ws + o); o += (size_t)BH_ * M_ * M_ / 2;
  short* yb1 = (short*)(ws + o); o += (size_t)BH_ * M_ * M_ / 2;
  short* p1b = (short*)(ws + o); o += (size_t)BH_ * M_ * M_ / 2;
  short* y2b = (short*)(ws + o); o += (size_t)BH_ * M_ * M_ / 2;
  short* wb  = (short*)(ws + o); o += (size_t)BH_ * M_ * M_ / 2;
  float* Opart = ws + o; o += (size_t)CH_ * 64 * 4096;
  float* mpart = ws + o; o += (size_t)CH_ * 64 * 64;
  float* lpart = ws + o; o += (size_t)CH_ * 64 * 64;
  float* a3v = ws + o; o += (size_t)BH_ * M_ * DH_;
  short* w2tb = (short*)(ws + o); o += (size_t)BH_ * M_ * DH_ / 2;
  short* omb = (short*)(ws + o);  o += (size_t)2 * N_ * DIM_ / 2;
  unsigned int* scalebits = (unsigned int*)(ws + o); o += 16;
  if (ws_size < o * sizeof(float)) return;

  (void)hipMemsetAsync(scalebits, 0, 64, stream);
  ln_kernel<<<2 * N_ / 4, 256, 0, stream>>>(x, gamma, beta, xnb);
  convt_kernel<<<dim3(3 * DIM_ / 32, DIM_ / 32), 256, 0, stream>>>(wqkv, wqkvt, DIM_, 3 * DIM_);
  convt_kernel<<<dim3(DIM_ / 32, DIM_ / 32), 256, 0, stream>>>(wout, woutt, DIM_, DIM_);
  qkv_mfma<<<dim3(2 * N_ / 128, 3 * DIM_ / 128), 256, 0, stream>>>(xnb, wqkvt, qb, kb, vb);
  vt_kernel<<<dim3(N_ / 32, 2, BH_), 256, 0, stream>>>(vb, vtb);

  landmark_kernel<<<BH_ * M_ * DH_ / 256, 256, 0, stream>>>(qb, kb, ql, kl, qlb, klb);
  sim2_softmax<<<dim3(M_, BH_), 256, 0, stream>>>(ql, kl, a2, a2b);
  colmax_kernel<<<BH_, 256, 0, stream>>>(a2, scalebits);
  transpose_scale<<<BH_ * M_ * M_ / 256, 256, 0, stream>>>(a2, zb0, scalebits);

  // a3 flash (independent of pinv)
  a3_flash<<<dim3(CH_, 4, BH_), 256, 0, stream>>>(qlb, kb, vtb, Opart, mpart, lpart);
  a3_combine<<<dim3(64, 4), 256, 0, stream>>>(Opart, mpart, lpart, a3v);

  // Newton-Schulz: single cooperative dispatch (12 grid.syncs instead of 12
  // kernel boundaries)
  {
    void* nsArgs[] = {(void*)&a2b, (void*)&zb0, (void*)&zb1, (void*)&yb0, (void*)&yb1,
                      (void*)&p1b, (void*)&y2b, (void*)&wb, (void*)&z0f};
    (void)hipLaunchCooperativeKernel((void*)ns_fused, dim3(512), dim3(256), nsArgs, 0, stream);
  }

  // w2tb = bf16((z @ a3v)^T)  (w2t fused into epilogue)
  gemm_nn64<<<dim3(M_ / 64, 1, BH_), 256, 0, stream>>>(
      z0f, M_, (long long)M_ * M_, a3v, (long long)M_ * DH_, w2tb, M_);

  // fused a1 @ w2 + band-MFMA depthwise conv -> omb bf16
  a1_conv<<<dim3(N_ / 64, BH_), 256, 0, stream>>>(qb, klb, w2tb, vtb, rk, omb);

  final_mfma<<<dim3(2 * N_ / 128, DIM_ / 128), 256, 0, stream>>>(omb, woutt, x, bout, y);
}

// Round 10
// 430.226 us; speedup vs baseline: 4.1006x; 4.1006x over previous
//
#include <hip/hip_runtime.h>
#include <math.h>

#define H_ 8
#define DH_ 64
#define DIM_ 512
#define M_ 256
#define N_ 8192
#define BH_ 16
#define LG_ 32
#define KC_ 33
#define CH_ 16   // a3 flash K-chunks
#define NTI_ 8   // 64-token tiles per chunk = N_/CH_/64

typedef __attribute__((ext_vector_type(8))) short bf16x8;
typedef __attribute__((ext_vector_type(4))) short s16x4;
typedef __attribute__((ext_vector_type(4))) float f32x4;

__device__ __forceinline__ short f2bf(float f) {
  unsigned u = __float_as_uint(f);
  unsigned r = (u + 0x7FFF + ((u >> 16) & 1)) >> 16;  // RNE
  return (short)r;
}
__device__ __forceinline__ float bf2f(short s) {
  return __uint_as_float(((unsigned)(unsigned short)s) << 16);
}

// =================== bf16 MFMA NT core (128x128 tile) ===================
__device__ __forceinline__ void mfma_nt_core(const short* __restrict__ A,
                                             const short* __restrict__ Bt, int K,
                                             int m0, int n0, size_t lda, size_t ldb,
                                             f32x4 acc[4][4], short* As, short* Bs) {
  const int tid = threadIdx.x;
  const int wave = tid >> 6, lane = tid & 63;
  const int wr = (wave >> 1) * 64, wc = (wave & 1) * 64;
  const int mi = lane & 15, quad = lane >> 4;
  for (int k0 = 0; k0 < K; k0 += 32) {
#pragma unroll
    for (int t = 0; t < 2; ++t) {
      const int cbase = (t * 4 + wave) * 64;
      const int chunk = cbase + lane;
      const int row = chunk >> 2, cc = (chunk & 3) * 8;
      __builtin_amdgcn_global_load_lds(
          (const __attribute__((address_space(1))) void*)(A + (size_t)(m0 + row) * lda + k0 + cc),
          (__attribute__((address_space(3))) void*)(As + (size_t)cbase * 8), 16, 0, 0);
      __builtin_amdgcn_global_load_lds(
          (const __attribute__((address_space(1))) void*)(Bt + (size_t)(n0 + row) * ldb + k0 + cc),
          (__attribute__((address_space(3))) void*)(Bs + (size_t)cbase * 8), 16, 0, 0);
    }
    __syncthreads();
    bf16x8 af[4], bf[4];
#pragma unroll
    for (int i = 0; i < 4; ++i)
      af[i] = *(const bf16x8*)&As[(wr + i * 16 + mi) * 32 + quad * 8];
#pragma unroll
    for (int j = 0; j < 4; ++j)
      bf[j] = *(const bf16x8*)&Bs[(wc + j * 16 + mi) * 32 + quad * 8];
#pragma unroll
    for (int i = 0; i < 4; ++i)
#pragma unroll
      for (int j = 0; j < 4; ++j)
        acc[i][j] = __builtin_amdgcn_mfma_f32_16x16x32_bf16(af[i], bf[j], acc[i][j], 0, 0, 0);
    __syncthreads();
  }
}

// QKV GEMM -> bf16 q/k/v (bh,n,d), q scaled
__global__ __launch_bounds__(256) void qkv_mfma(const short* __restrict__ xnb,
                                                const short* __restrict__ wt,
                                                short* __restrict__ qb, short* __restrict__ kb,
                                                short* __restrict__ vb) {
  __shared__ short As[128 * 32], Bs[128 * 32];
  f32x4 acc[4][4] = {};
  const int m0 = blockIdx.x * 128, n0 = blockIdx.y * 128;
  mfma_nt_core(xnb, wt, DIM_, m0, n0, DIM_, DIM_, acc, As, Bs);
  const int wave = threadIdx.x >> 6, lane = threadIdx.x & 63;
  const int wr = (wave >> 1) * 64, wc = (wave & 1) * 64;
  const int mi = lane & 15, quad = lane >> 4;
  const int which = n0 >> 9;
  short* dst = which == 0 ? qb : which == 1 ? kb : vb;
  const float sc = which == 0 ? 0.125f : 1.0f;
#pragma unroll
  for (int j = 0; j < 4; ++j) {
    const int col = n0 + wc + j * 16 + mi;
    const int h = (col >> 6) & 7, d = col & 63;
#pragma unroll
    for (int i = 0; i < 4; ++i) {
#pragma unroll
      for (int r = 0; r < 4; ++r) {
        const int row = m0 + wr + i * 16 + quad * 4 + r;
        const int b = row >> 13, t = row & (N_ - 1);
        dst[((size_t)(b * H_ + h) * N_ + t) * DH_ + d] = f2bf(acc[i][j][r] * sc);
      }
    }
  }
}

// final: y = x + omb @ woutt^T + b_out
__global__ __launch_bounds__(256) void final_mfma(const short* __restrict__ omb,
                                                  const short* __restrict__ wt,
                                                  const float* __restrict__ x,
                                                  const float* __restrict__ bout,
                                                  float* __restrict__ y) {
  __shared__ short As[128 * 32], Bs[128 * 32];
  f32x4 acc[4][4] = {};
  const int m0 = blockIdx.x * 128, n0 = blockIdx.y * 128;
  mfma_nt_core(omb, wt, DIM_, m0, n0, DIM_, DIM_, acc, As, Bs);
  const int wave = threadIdx.x >> 6, lane = threadIdx.x & 63;
  const int wr = (wave >> 1) * 64, wc = (wave & 1) * 64;
  const int mi = lane & 15, quad = lane >> 4;
#pragma unroll
  for (int j = 0; j < 4; ++j) {
    const int col = n0 + wc + j * 16 + mi;
    const float bo = bout[col];
#pragma unroll
    for (int i = 0; i < 4; ++i) {
#pragma unroll
      for (int r = 0; r < 4; ++r) {
        const int row = m0 + wr + i * 16 + quad * 4 + r;
        y[(size_t)row * DIM_ + col] = acc[i][j][r] + x[(size_t)row * DIM_ + col] + bo;
      }
    }
  }
}

// fp32 (K x N) -> bf16 transposed (N x K)
__global__ __launch_bounds__(256) void convt_kernel(const float* __restrict__ in,
                                                    short* __restrict__ out, int K, int N) {
  __shared__ float tile[32][33];
  const int n0 = blockIdx.x * 32, k0 = blockIdx.y * 32;
  const int tx = threadIdx.x & 31, ty = threadIdx.x >> 5;
  for (int r = ty; r < 32; r += 8) tile[r][tx] = in[(size_t)(k0 + r) * N + n0 + tx];
  __syncthreads();
  for (int r = ty; r < 32; r += 8) out[(size_t)(n0 + r) * K + k0 + tx] = f2bf(tile[tx][r]);
}

// bf16 v (bh,t,d) -> vtb (bh,d,t): 32x32 LDS tiles, conflict-free (+1 pad)
__global__ __launch_bounds__(256) void vt_kernel(const short* __restrict__ vb,
                                                 short* __restrict__ vtb) {
  __shared__ short tile[32][33];
  const int t0 = blockIdx.x * 32, d0 = blockIdx.y * 32, bh = blockIdx.z;
  const int tx = threadIdx.x & 31, ty = threadIdx.x >> 5;
  for (int r = ty; r < 32; r += 8)
    tile[r][tx] = vb[((size_t)bh * N_ + t0 + r) * DH_ + d0 + tx];
  __syncthreads();
  for (int r = ty; r < 32; r += 8)
    vtb[((size_t)bh * DH_ + d0 + r) * N_ + t0 + tx] = tile[tx][r];
}

// ---------------- LayerNorm -> bf16 (wave-per-row, shfl reduce, no LDS) ----------------
__global__ __launch_bounds__(256) void ln_kernel(const float* __restrict__ x,
                                                 const float* __restrict__ gamma,
                                                 const float* __restrict__ beta,
                                                 short* __restrict__ xnb) {
  const int row = blockIdx.x * 4 + (threadIdx.x >> 6);
  const int lane = threadIdx.x & 63;
  const float4* xr = (const float4*)(x + (size_t)row * DIM_) + lane * 2;
  const float4 v0 = xr[0], v1 = xr[1];
  float s = v0.x + v0.y + v0.z + v0.w + v1.x + v1.y + v1.z + v1.w;
  float ss = v0.x * v0.x + v0.y * v0.y + v0.z * v0.z + v0.w * v0.w +
             v1.x * v1.x + v1.y * v1.y + v1.z * v1.z + v1.w * v1.w;
#pragma unroll
  for (int off = 1; off < 64; off <<= 1) {
    s += __shfl_xor(s, off, 64);
    ss += __shfl_xor(ss, off, 64);
  }
  const float mu = s * (1.0f / DIM_);
  const float var = ss * (1.0f / DIM_) - mu * mu;
  const float rs = rsqrtf(var + 1e-5f);
  const float4 g0 = ((const float4*)gamma)[lane * 2], g1 = ((const float4*)gamma)[lane * 2 + 1];
  const float4 b0 = ((const float4*)beta)[lane * 2], b1 = ((const float4*)beta)[lane * 2 + 1];
  bf16x8 o;
  o[0] = f2bf((v0.x - mu) * rs * g0.x + b0.x);
  o[1] = f2bf((v0.y - mu) * rs * g0.y + b0.y);
  o[2] = f2bf((v0.z - mu) * rs * g0.z + b0.z);
  o[3] = f2bf((v0.w - mu) * rs * g0.w + b0.w);
  o[4] = f2bf((v1.x - mu) * rs * g1.x + b1.x);
  o[5] = f2bf((v1.y - mu) * rs * g1.y + b1.y);
  o[6] = f2bf((v1.z - mu) * rs * g1.z + b1.z);
  o[7] = f2bf((v1.w - mu) * rs * g1.w + b1.w);
  *(bf16x8*)(xnb + (size_t)row * DIM_ + lane * 8) = o;
}

// ---------------- landmarks ----------------
__global__ __launch_bounds__(256) void landmark_kernel(const short* __restrict__ qb,
                                                       const short* __restrict__ kb,
                                                       float* __restrict__ ql,
                                                       float* __restrict__ kl,
                                                       short* __restrict__ qlb,
                                                       short* __restrict__ klb) {
  const int idx = blockIdx.x * 256 + threadIdx.x;
  const int d = idx & (DH_ - 1);
  const int m = (idx >> 6) & (M_ - 1);
  const int bh = idx >> 14;
  const size_t base = ((size_t)bh * N_ + m * LG_) * DH_ + d;
  float sq = 0.f, sk = 0.f;
#pragma unroll 8
  for (int t = 0; t < LG_; ++t) {
    sq += bf2f(qb[base + (size_t)t * DH_]);
    sk += bf2f(kb[base + (size_t)t * DH_]);
  }
  sq *= (1.0f / LG_);
  sk *= (1.0f / LG_);
  ql[idx] = sq;
  kl[idx] = sk;
  qlb[idx] = f2bf(sq);
  klb[idx] = f2bf(sk);
}

// ---------------- sim2 + softmax ----------------
__global__ __launch_bounds__(256) void sim2_softmax(const float* __restrict__ ql,
                                                    const float* __restrict__ kl,
                                                    float* __restrict__ a2,
                                                    short* __restrict__ a2b) {
  const int i = blockIdx.x, bh = blockIdx.y, j = threadIdx.x;
  __shared__ float qrow[DH_];
  if (j < DH_) qrow[j] = ql[((size_t)bh * M_ + i) * DH_ + j];
  __syncthreads();
  const float* kr = kl + ((size_t)bh * M_ + j) * DH_;
  float s = 0.f;
#pragma unroll 16
  for (int d = 0; d < DH_; ++d) s += qrow[d] * kr[d];
  __shared__ float red[256];
  red[j] = s;
  __syncthreads();
  for (int off = 128; off > 0; off >>= 1) {
    if (j < off) red[j] = fmaxf(red[j], red[j + off]);
    __syncthreads();
  }
  const float mx = red[0];
  __syncthreads();
  const float e = expf(s - mx);
  red[j] = e;
  __syncthreads();
  for (int off = 128; off > 0; off >>= 1) {
    if (j < off) red[j] += red[j + off];
    __syncthreads();
  }
  const float out = e / red[0];
  a2[((size_t)bh * M_ + i) * M_ + j] = out;
  a2b[((size_t)bh * M_ + i) * M_ + j] = f2bf(out);
}

__global__ __launch_bounds__(256) void colmax_kernel(const float* __restrict__ a2,
                                                     unsigned int* __restrict__ scalebits) {
  const int bh = blockIdx.x, j = threadIdx.x;
  const float* mat = a2 + (size_t)bh * M_ * M_;
  float s = 0.f;
  for (int i = 0; i < M_; ++i) s += fabsf(mat[i * M_ + j]);
  __shared__ float red[256];
  red[j] = s;
  __syncthreads();
  for (int off = 128; off > 0; off >>= 1) {
    if (j < off) red[j] = fmaxf(red[j], red[j + off]);
    __syncthreads();
  }
  if (j == 0) atomicMax(scalebits, __float_as_uint(red[0]));
}

// z0b = bf16(a2^T / scale)
__global__ __launch_bounds__(256) void transpose_scale(const float* __restrict__ a2,
                                                       short* __restrict__ z0b,
                                                       const unsigned int* __restrict__ scalebits) {
  const float inv = 1.0f / __uint_as_float(*scalebits);
  const int idx = blockIdx.x * 256 + threadIdx.x;
  const int j = idx & (M_ - 1), i = (idx >> 8) & (M_ - 1), bh = idx >> 16;
  z0b[idx] = f2bf(a2[((size_t)bh * M_ + j) * M_ + i] * inv);
}

// ============ Newton-Schulz bf16 MFMA machinery (64x64 tiles of 256^2, K=256) ============
// ONE barrier per GEMM. A-frags direct from global into af[8] regs (lane-private
// rows). B reg-staged in one shot then LDS stride-260. LDS 33,280 B.
__device__ __forceinline__ void ns_core(const short* __restrict__ A, const short* __restrict__ B,
                                        int m0, int n0, short* Bs, f32x4 acc[4]) {
  const int tid = threadIdx.x, wave = tid >> 6, lane = tid & 63;
  const int mi = lane & 15, quad = lane >> 4;
  const int bkk = tid & 31, g = tid >> 5;
  bf16x8 bv[8];
#pragma unroll
  for (int kc = 0; kc < 8; ++kc)
    bv[kc] = *(const bf16x8*)(B + (size_t)(kc * 32 + bkk) * M_ + n0 + g * 8);
  const short* arow = A + (size_t)(m0 + wave * 16 + mi) * M_;
  bf16x8 af[8];
#pragma unroll
  for (int k0 = 0; k0 < 8; ++k0)
    af[k0] = *(const bf16x8*)(arow + k0 * 32 + quad * 8);
#pragma unroll
  for (int kc = 0; kc < 8; ++kc)
#pragma unroll
    for (int e = 0; e < 8; ++e)
      Bs[(g * 8 + e) * 260 + kc * 32 + bkk] = bv[kc][e];
  __syncthreads();
#pragma unroll
  for (int k0 = 0; k0 < 8; ++k0) {
#pragma unroll
    for (int j = 0; j < 4; ++j) {
      union { bf16x8 v; s16x4 h[2]; } bfr;
      const short* bp = &Bs[(j * 16 + mi) * 260 + k0 * 32 + quad * 8];
      bfr.h[0] = *(const s16x4*)bp;
      bfr.h[1] = *(const s16x4*)(bp + 4);
      acc[j] = __builtin_amdgcn_mfma_f32_16x16x32_bf16(af[k0], bfr.v, acc[j], 0, 0, 0);
    }
  }
}

// XCD-aware bijective remap (T1)
__device__ __forceinline__ int ns_remap() {
  const int lin = blockIdx.y * 16 + blockIdx.x;
  return (lin & 7) * (gridDim.y << 1) + (lin >> 3);
}

// y0 = A@B
__global__ __launch_bounds__(256) void ns_gemm0(const short* __restrict__ A,
                                                const short* __restrict__ B,
                                                short* __restrict__ C) {
  __shared__ short Bs[64 * 260];
  const int id = ns_remap();
  const int bx = id & 15, by = id >> 4;
  const int m0 = (bx >> 2) * 64, n0 = (bx & 3) * 64;
  const size_t mo = (size_t)by * (M_ * M_);
  f32x4 acc[4] = {};
  ns_core(A + mo, B + mo, m0, n0, Bs, acc);
  const int wave = threadIdx.x >> 6, lane = threadIdx.x & 63;
  const int mi = lane & 15, quad = lane >> 4;
#pragma unroll
  for (int j = 0; j < 4; ++j)
#pragma unroll
    for (int r = 0; r < 4; ++r) {
      const int row = m0 + wave * 16 + quad * 4 + r, col = n0 + j * 16 + mi;
      C[mo + (size_t)row * M_ + col] = f2bf(acc[j][r]);
    }
}

// stage A: sel0: p1 = z@y ; sel1: y2 = y@y, w = 1.75y - 0.25*y2
__global__ __launch_bounds__(256) void ns_stageA(const short* __restrict__ z,
                                                 const short* __restrict__ y,
                                                 short* __restrict__ p1,
                                                 short* __restrict__ y2,
                                                 short* __restrict__ w) {
  __shared__ short Bs[64 * 260];
  const int id = ns_remap();
  const int bx = id & 15, by = id >> 4;
  const int m0 = (bx >> 2) * 64, n0 = (bx & 3) * 64;
  const int sel = by & 1;
  const size_t mo = (size_t)(by >> 1) * (M_ * M_);
  f32x4 acc[4] = {};
  ns_core((sel ? y : z) + mo, y + mo, m0, n0, Bs, acc);
  const int wave = threadIdx.x >> 6, lane = threadIdx.x & 63;
  const int mi = lane & 15, quad = lane >> 4;
#pragma unroll
  for (int j = 0; j < 4; ++j)
#pragma unroll
    for (int r = 0; r < 4; ++r) {
      const int row = m0 + wave * 16 + quad * 4 + r, col = n0 + j * 16 + mi;
      const size_t idx = mo + (size_t)row * M_ + col;
      if (sel) {
        y2[idx] = f2bf(acc[j][r]);
        w[idx] = f2bf(1.75f * bf2f(y[idx]) - 0.25f * acc[j][r]);
      } else {
        p1[idx] = f2bf(acc[j][r]);
      }
    }
}

// stage B: sel0: zo = 3.25z - 3.75p1 + p1@w (opt fp32 out) ; sel1: yo = 3.25y - 3.75y2 + y2@w
__global__ __launch_bounds__(256) void ns_stageB(const short* __restrict__ p1,
                                                 const short* __restrict__ y2,
                                                 const short* __restrict__ w,
                                                 const short* __restrict__ z,
                                                 const short* __restrict__ y,
                                                 short* __restrict__ zo,
                                                 short* __restrict__ yo,
                                                 float* __restrict__ zf, int zonly) {
  __shared__ short Bs[64 * 260];
  const int id = ns_remap();
  const int bx = id & 15, by = id >> 4;
  const int m0 = (bx >> 2) * 64, n0 = (bx & 3) * 64;
  const int sel = zonly ? 0 : (by & 1);
  const size_t mo = (size_t)(zonly ? by : (by >> 1)) * (M_ * M_);
  f32x4 acc[4] = {};
  ns_core((sel ? y2 : p1) + mo, w + mo, m0, n0, Bs, acc);
  const int wave = threadIdx.x >> 6, lane = threadIdx.x & 63;
  const int mi = lane & 15, quad = lane >> 4;
#pragma unroll
  for (int j = 0; j < 4; ++j)
#pragma unroll
    for (int r = 0; r < 4; ++r) {
      const int row = m0 + wave * 16 + quad * 4 + r, col = n0 + j * 16 + mi;
      const size_t idx = mo + (size_t)row * M_ + col;
      if (sel) {
        yo[idx] = f2bf(3.25f * bf2f(y[idx]) - 3.75f * bf2f(y2[idx]) + acc[j][r]);
      } else {
        const float v = 3.25f * bf2f(z[idx]) - 3.75f * bf2f(p1[idx]) + acc[j][r];
        zo[idx] = f2bf(v);
        if (zf) zf[idx] = v;
      }
    }
}

// ---------------- fp32 64x64 core (w2 = z @ a3v, writes bf16 TRANSPOSED) ----------------
__device__ __forceinline__ void mm_step(float (*As)[68], float (*Bs)[68],
                                        int tr, int tc, float acc[4][4]) {
#pragma unroll
  for (int kk = 0; kk < 16; ++kk) {
    const float4 a4 = *(const float4*)&As[kk][tr * 4];
    const float4 b4 = *(const float4*)&Bs[kk][tc * 4];
    const float a[4] = {a4.x, a4.y, a4.z, a4.w};
    const float b[4] = {b4.x, b4.y, b4.z, b4.w};
#pragma unroll
    for (int i = 0; i < 4; ++i)
#pragma unroll
      for (int j = 0; j < 4; ++j) acc[i][j] = fmaf(a[i], b[j], acc[i][j]);
  }
}

__device__ __forceinline__ void load_a_tile(const float* A, int lda, int m0, int k0,
                                            int tid, float (*As)[68]) {
  const int r = tid >> 2, kq = tid & 3;
  const float4 a4 = *(const float4*)(A + (size_t)(m0 + r) * lda + k0 + kq * 4);
  As[kq * 4 + 0][r] = a4.x;
  As[kq * 4 + 1][r] = a4.y;
  As[kq * 4 + 2][r] = a4.z;
  As[kq * 4 + 3][r] = a4.w;
}

__device__ __forceinline__ void load_b_nn(const float* B, int ldb, int k0, int n0,
                                          int tid, float (*Bs)[68]) {
  const int kr = tid >> 4, c4 = tid & 15;
  const float4 b4 = *(const float4*)(B + (size_t)(k0 + kr) * ldb + n0 + c4 * 4);
  *(float4*)&Bs[kr][c4 * 4] = b4;
}

// w2tb[bh][d][M] = (z0f[bh] @ a3v[bh])^T in bf16 (w2t fused into epilogue)
__global__ __launch_bounds__(256) void gemm_nn64(const float* __restrict__ A, int lda,
                                                 long long strideA,
                                                 const float* __restrict__ B, long long strideB,
                                                 short* __restrict__ w2tb, int kchunk) {
  const int bz = blockIdx.z;
  A += (size_t)bz * strideA;
  B += (size_t)bz * strideB;
  const int m0 = blockIdx.x * 64;
  const int tid = threadIdx.x, tr = tid >> 4, tc = tid & 15;
  __shared__ float As[16][68], Bs[16][68];
  float acc[4][4] = {};
  for (int k0 = 0; k0 < kchunk; k0 += 16) {
    load_a_tile(A, lda, m0, k0, tid, As);
    load_b_nn(B, DH_, k0, 0, tid, Bs);
    __syncthreads();
    mm_step(As, Bs, tr, tc, acc);
    __syncthreads();
  }
#pragma unroll
  for (int i = 0; i < 4; ++i) {
    const int row = m0 + tr * 4 + i;
#pragma unroll
    for (int j = 0; j < 4; ++j)
      w2tb[((size_t)bz * DH_ + tc * 4 + j) * M_ + row] = f2bf(acc[i][j]);
  }
}

// ---------------- a3 flash (double-buffered ks + staged vs, 1 barrier/iter) ----------------
__device__ __forceinline__ void stage_ks(const short* __restrict__ kb, int bh, int n0,
                                         int wave, int lane, short* ks) {
#pragma unroll
  for (int i = 0; i < 2; ++i) {
    const int cb = i * 256 + wave * 64;
    const int c = cb + lane;
    const int row = c >> 3, cc = c & 7;
    __builtin_amdgcn_global_load_lds(
        (const __attribute__((address_space(1))) void*)(
            kb + ((size_t)bh * N_ + n0 + row) * DH_ + ((cc ^ (row & 7)) * 8)),
        (__attribute__((address_space(3))) void*)(ks + (size_t)cb * 8), 16, 0, 0);
  }
}

__device__ __forceinline__ void stage_vs(const short* __restrict__ vtb, int bh, int n0,
                                         int wave, int lane, short* vs) {
#pragma unroll
  for (int i = 0; i < 2; ++i) {
    const int cb = i * 256 + wave * 64;
    const int c = cb + lane;
    const int row = c >> 3, cc = c & 7;  // row = d index
    __builtin_amdgcn_global_load_lds(
        (const __attribute__((address_space(1))) void*)(
            vtb + ((size_t)bh * DH_ + row) * N_ + n0 + ((cc ^ (row & 7)) * 8)),
        (__attribute__((address_space(3))) void*)(vs + (size_t)cb * 8), 16, 0, 0);
  }
}

__global__ __launch_bounds__(256) void a3_flash(const short* __restrict__ qlb,
                                                const short* __restrict__ kb,
                                                const short* __restrict__ vtb,
                                                float* __restrict__ Opart,
                                                float* __restrict__ mpart,
                                                float* __restrict__ lpart) {
  const int chunk = blockIdx.x, rt = blockIdx.y, bh = blockIdx.z;
  __shared__ short ks[2][64 * 64];
  __shared__ short vs[2][64 * 64];
  __shared__ short ps[64 * 64];
  const int tid = threadIdx.x, wave = tid >> 6, lane = tid & 63;
  const int mi = lane & 15, quad = lane >> 4;
  // q frags direct from global (lane-private rows)
  const short* qrow = qlb + ((size_t)bh * M_ + rt * 64 + wave * 16 + mi) * DH_;
  const bf16x8 aq0 = *(const bf16x8*)(qrow + quad * 8);
  const bf16x8 aq1 = *(const bf16x8*)(qrow + 32 + quad * 8);
  float m[4] = {-INFINITY, -INFINITY, -INFINITY, -INFINITY};
  float l[4] = {0.f, 0.f, 0.f, 0.f};  // per-lane PARTIAL sums (reduced at epilogue)
  f32x4 o[4] = {};
  const int nbase = chunk * (N_ / CH_);
  stage_ks(kb, bh, nbase, wave, lane, ks[0]);
  stage_vs(vtb, bh, nbase, wave, lane, vs[0]);
  __syncthreads();  // vmcnt drained -> buf0 ready
  for (int t = 0; t < NTI_; ++t) {
    const int cur = t & 1;
    if (t + 1 < NTI_) {
      stage_ks(kb, bh, nbase + (t + 1) * 64, wave, lane, ks[cur ^ 1]);
      stage_vs(vtb, bh, nbase + (t + 1) * 64, wave, lane, vs[cur ^ 1]);
    }
    f32x4 s[4];
#pragma unroll
    for (int j = 0; j < 4; ++j) {
      const int row = j * 16 + mi;
      const bf16x8 b0 = *(const bf16x8*)&ks[cur][row * 64 + ((quad ^ (row & 7)) * 8)];
      const bf16x8 b1 = *(const bf16x8*)&ks[cur][row * 64 + (((quad + 4) ^ (row & 7)) * 8)];
      f32x4 z = {0.f, 0.f, 0.f, 0.f};
      z = __builtin_amdgcn_mfma_f32_16x16x32_bf16(aq0, b0, z, 0, 0, 0);
      s[j] = __builtin_amdgcn_mfma_f32_16x16x32_bf16(aq1, b1, z, 0, 0, 0);
    }
    float alpha[4];
#pragma unroll
    for (int r = 0; r < 4; ++r) {
      float v = fmaxf(fmaxf(s[0][r], s[1][r]), fmaxf(s[2][r], s[3][r]));
      v = fmaxf(v, __shfl_xor(v, 1, 64));
      v = fmaxf(v, __shfl_xor(v, 2, 64));
      v = fmaxf(v, __shfl_xor(v, 4, 64));
      v = fmaxf(v, __shfl_xor(v, 8, 64));
      const float mnew = fmaxf(m[r], v);
      alpha[r] = __expf(m[r] - mnew);
      m[r] = mnew;
    }
    float rs[4] = {0.f, 0.f, 0.f, 0.f};
#pragma unroll
    for (int j = 0; j < 4; ++j)
#pragma unroll
      for (int r = 0; r < 4; ++r) {
        const float p = __expf(s[j][r] - m[r]);
        rs[r] += p;
        const int prow = wave * 16 + quad * 4 + r;
        const int pcol = j * 16 + mi;
        ps[prow * 64 + (((pcol >> 3) ^ (prow & 7)) * 8) + (pcol & 7)] = f2bf(p);
      }
#pragma unroll
    for (int r = 0; r < 4; ++r) {
      l[r] = l[r] * alpha[r] + rs[r];  // per-lane partial (alpha row-uniform)
#pragma unroll
      for (int j = 0; j < 4; ++j) o[j][r] *= alpha[r];
    }
    // ps row stripe wave-private: in-order DS pipe orders write->read
    const int prow = wave * 16 + mi;
    const bf16x8 ap0 = *(const bf16x8*)&ps[prow * 64 + ((quad ^ (mi & 7)) * 8)];
    const bf16x8 ap1 = *(const bf16x8*)&ps[prow * 64 + (((quad + 4) ^ (mi & 7)) * 8)];
#pragma unroll
    for (int j = 0; j < 4; ++j) {
      const int vrow = j * 16 + mi;
      const bf16x8 b0 = *(const bf16x8*)&vs[cur][vrow * 64 + ((quad ^ (vrow & 7)) * 8)];
      const bf16x8 b1 = *(const bf16x8*)&vs[cur][vrow * 64 + (((quad + 4) ^ (vrow & 7)) * 8)];
      o[j] = __builtin_amdgcn_mfma_f32_16x16x32_bf16(ap0, b0, o[j], 0, 0, 0);
      o[j] = __builtin_amdgcn_mfma_f32_16x16x32_bf16(ap1, b1, o[j], 0, 0, 0);
    }
    __syncthreads();  // single barrier: drains next-tile vmcnt + closes WAR on cur
  }
#pragma unroll
  for (int r = 0; r < 4; ++r) {
    float v = l[r];
    v += __shfl_xor(v, 1, 64);
    v += __shfl_xor(v, 2, 64);
    v += __shfl_xor(v, 4, 64);
    v += __shfl_xor(v, 8, 64);
    l[r] = v;
  }
  const int p2 = bh * 4 + rt;
  float* Ob = Opart + ((size_t)chunk * 64 + p2) * 4096;
#pragma unroll
  for (int j = 0; j < 4; ++j)
#pragma unroll
    for (int r = 0; r < 4; ++r)
      Ob[(wave * 16 + quad * 4 + r) * 64 + j * 16 + mi] = o[j][r];
  if (mi == 0) {
#pragma unroll
    for (int r = 0; r < 4; ++r) {
      mpart[((size_t)chunk * 64 + p2) * 64 + wave * 16 + quad * 4 + r] = m[r];
      lpart[((size_t)chunk * 64 + p2) * 64 + wave * 16 + quad * 4 + r] = l[r];
    }
  }
}

// grid (64, 4): each block combines one p2 over a quarter of the 64x64 output
__global__ __launch_bounds__(256) void a3_combine(const float* __restrict__ Opart,
                                                  const float* __restrict__ mpart,
                                                  const float* __restrict__ lpart,
                                                  float* __restrict__ a3v) {
  const int p2 = blockIdx.x, ds = blockIdx.y;
  const int bh = p2 >> 2, rt = p2 & 3;
  __shared__ float wgt[CH_][64];
  const int tid = threadIdx.x;
  if (tid < 64) {
    float mg = -INFINITY;
#pragma unroll
    for (int c = 0; c < CH_; ++c) mg = fmaxf(mg, mpart[((size_t)c * 64 + p2) * 64 + tid]);
    float e[CH_], lg = 0.f;
#pragma unroll
    for (int c = 0; c < CH_; ++c) {
      e[c] = __expf(mpart[((size_t)c * 64 + p2) * 64 + tid] - mg);
      lg += lpart[((size_t)c * 64 + p2) * 64 + tid] * e[c];
    }
    const float inv = 1.f / lg;
#pragma unroll
    for (int c = 0; c < CH_; ++c) wgt[c][tid] = e[c] * inv;
  }
  __syncthreads();
  for (int i = ds * 1024 + tid; i < ds * 1024 + 1024; i += 256) {
    const int row = i >> 6, d = i & 63;
    float s = 0.f;
#pragma unroll
    for (int c = 0; c < CH_; ++c) s += Opart[((size_t)c * 64 + p2) * 4096 + i] * wgt[c][row];
    a3v[((size_t)bh * M_ + rt * 64 + row) * DH_ + d] = s;
  }
}

// ---------------- a1 fused: omb = softmax(q @ kl^T) @ w2 + Band@Vwin (conv) ----------------
// Measured-best (R6): single staging of ALL 256 landmarks (8 gload_lds in
// flight, one wait), T14 vwin (global loads to regs at kernel start, LDS write
// after post-QK barrier into a region disjoint from ps), deferred
// sum-normalization. 3 barriers total. LDS layout (34,944 B, 4 blocks/CU):
//   kls [0,32768)  = [256][64] staged          (dead after QK)
//   ps  [0,17920)  = [64][140]  aliases kls    (wave-private stripes)
//   vwin[17920,32768) = [64][116] aliases kls  (disjoint from ps!)
//   band[32768,34944) = [16][68]
__global__ __launch_bounds__(256, 4) void a1_conv(const short* __restrict__ qb,
                                                  const short* __restrict__ klb,
                                                  const short* __restrict__ w2tb,
                                                  const short* __restrict__ vtb,
                                                  const float* __restrict__ rk,
                                                  short* __restrict__ omb) {
  __shared__ __align__(16) char smem[34944];
  short* kls = (short*)smem;
  short* ps = (short*)smem;
  short* vwin = (short*)(smem + 17920);
  short* band = (short*)(smem + 32768);
  const int bh = blockIdx.y, t0 = blockIdx.x * 64;
  const int b = bh >> 3, h = bh & 7;
  const int tid = threadIdx.x, wave = tid >> 6, lane = tid & 63;
  const int mi = lane & 15, quad = lane >> 4;

  // q A-frags direct from global (wave-private rows, no reuse)
  const short* qrow = qb + ((size_t)bh * N_ + t0 + wave * 16 + mi) * DH_;
  const bf16x8 aq0 = *(const bf16x8*)(qrow + quad * 8);
  const bf16x8 aq1 = *(const bf16x8*)(qrow + 32 + quad * 8);

  // T14 vwin: issue global loads into REGISTERS now; LDS write happens after
  // the post-QK barrier -> HBM latency hides under staging+QK+softmax.
  const int vd = tid & 63, cg0 = tid >> 6;
  bf16x8 vreg[4];
  {
    const short* vrow = vtb + ((size_t)bh * DH_ + vd) * N_;
#pragma unroll
    for (int slot = 0; slot < 4; ++slot) {
      const int ch = cg0 + slot * 4;
      bf16x8 vv = {};
      if (ch < 14) {
        const int tbase = t0 - 16 + ch * 8;
        if (tbase >= 0 && tbase + 8 <= N_) {
          vv = *(const bf16x8*)(vrow + tbase);
        } else {
#pragma unroll
          for (int e = 0; e < 8; ++e) {
            const int tt = tbase + e;
            vv[e] = (tt >= 0 && tt < N_) ? vrow[tt] : (short)0;
          }
        }
      }
      vreg[slot] = vv;
    }
  }
  // band build (disjoint region, covered by bar1)
#pragma unroll
  for (int i = 0; i < 4; ++i) {
    const int idx = tid + i * 256;  // < 1024
    const int r = idx >> 6, c = idx & 63, u = c - r;
    band[r * 68 + c] = (u >= 0 && u < KC_) ? f2bf(rk[h * KC_ + u]) : (short)0;
  }

  // stage ALL 256 landmark rows (8 gload_lds/thread, source-side XOR swizzle)
#pragma unroll
  for (int i = 0; i < 8; ++i) {
    const int cb = i * 256 + wave * 64;  // wave-uniform chunk base
    const int c = cb + lane;
    const int row = c >> 3, cc = c & 7;
    __builtin_amdgcn_global_load_lds(
        (const __attribute__((address_space(1))) void*)(
            klb + ((size_t)bh * M_ + row) * DH_ + (cc ^ (row & 7)) * 8),
        (__attribute__((address_space(3))) void*)(kls + (size_t)cb * 8), 16, 0, 0);
  }
  __syncthreads();  // bar1: staging (and band) complete

  // QK over all 256 landmarks
  f32x4 s[16] = {};
#pragma unroll
  for (int f = 0; f < 16; ++f) {
    const int row = f * 16 + mi;
    const bf16x8 blo = *(const bf16x8*)&kls[row * 64 + ((quad ^ (row & 7)) * 8)];
    const bf16x8 bhi = *(const bf16x8*)&kls[row * 64 + (((quad + 4) ^ (row & 7)) * 8)];
    f32x4 z = __builtin_amdgcn_mfma_f32_16x16x32_bf16(aq0, blo, s[f], 0, 0, 0);
    s[f] = __builtin_amdgcn_mfma_f32_16x16x32_bf16(aq1, bhi, z, 0, 0, 0);
  }
  // exact softmax: max reduce + exp; sum kept as per-lane partial (deferred)
  float lsum[4];
#pragma unroll
  for (int r = 0; r < 4; ++r) {
    float v = s[0][r];
#pragma unroll
    for (int f = 1; f < 16; ++f) v = fmaxf(v, s[f][r]);
    v = fmaxf(v, __shfl_xor(v, 1, 64));
    v = fmaxf(v, __shfl_xor(v, 2, 64));
    v = fmaxf(v, __shfl_xor(v, 4, 64));
    v = fmaxf(v, __shfl_xor(v, 8, 64));
    float sum = 0.f;
#pragma unroll
    for (int f = 0; f < 16; ++f) {
      const float p = __expf(s[f][r] - v);
      s[f][r] = p;
      sum += p;
    }
    lsum[r] = sum;
  }
  __syncthreads();  // bar2: kls reads done by ALL waves; ps+vwin regions free

  // vwin LDS write from prefetched registers (region disjoint from ps)
#pragma unroll
  for (int slot = 0; slot < 4; ++slot) {
    const int ch = cg0 + slot * 4;
    if (ch < 14) *(bf16x8*)&vwin[vd * 116 + ch * 8] = vreg[slot];
  }

  // PV in two halves with UNNORMALIZED p (wave-private ps stripes, no barriers)
  f32x4 o[4] = {};
#pragma unroll
  for (int half = 0; half < 2; ++half) {
#pragma unroll
    for (int f = 0; f < 8; ++f)
#pragma unroll
      for (int r = 0; r < 4; ++r)
        ps[(wave * 16 + quad * 4 + r) * 140 + f * 16 + mi] = f2bf(s[half * 8 + f][r]);
#pragma unroll
    for (int k0 = 0; k0 < 4; ++k0) {
      union { bf16x8 v; s16x4 hh[2]; } ap;
      const short* pp = &ps[(wave * 16 + mi) * 140 + k0 * 32 + quad * 8];
      ap.hh[0] = *(const s16x4*)pp;
      ap.hh[1] = *(const s16x4*)(pp + 4);
#pragma unroll
      for (int j = 0; j < 4; ++j) {
        const bf16x8 bw = *(const bf16x8*)(w2tb + ((size_t)bh * DH_ + j * 16 + mi) * M_ +
                                           (half * 4 + k0) * 32 + quad * 8);
        o[j] = __builtin_amdgcn_mfma_f32_16x16x32_bf16(ap.v, bw, o[j], 0, 0, 0);
      }
    }
  }
  // deferred sum reduce + normalization (before conv add)
#pragma unroll
  for (int r = 0; r < 4; ++r) {
    float v = lsum[r];
    v += __shfl_xor(v, 1, 64);
    v += __shfl_xor(v, 2, 64);
    v += __shfl_xor(v, 4, 64);
    v += __shfl_xor(v, 8, 64);
    const float inv = 1.f / v;
#pragma unroll
    for (int j = 0; j < 4; ++j) o[j][r] *= inv;
  }
  __syncthreads();  // bar3: vwin writes visible to all waves

  // conv: o += Band(16x64) @ Vwin-slice (wave-offset window)
#pragma unroll
  for (int ks = 0; ks < 2; ++ks) {
    union { bf16x8 v; s16x4 hh[2]; } ab;
    const short* bp = &band[mi * 68 + ks * 32 + quad * 8];
    ab.hh[0] = *(const s16x4*)bp;
    ab.hh[1] = *(const s16x4*)(bp + 4);
#pragma unroll
    for (int j = 0; j < 4; ++j) {
      union { bf16x8 v; s16x4 hh[2]; } bv;
      const short* vp = &vwin[(j * 16 + mi) * 116 + wave * 16 + ks * 32 + quad * 8];
      bv.hh[0] = *(const s16x4*)vp;
      bv.hh[1] = *(const s16x4*)(vp + 4);
      o[j] = __builtin_amdgcn_mfma_f32_16x16x32_bf16(ab.v, bv.v, o[j], 0, 0, 0);
    }
  }
  // epilogue
#pragma unroll
  for (int j = 0; j < 4; ++j) {
    const int d = j * 16 + mi;
#pragma unroll
    for (int r = 0; r < 4; ++r) {
      const int t = t0 + wave * 16 + quad * 4 + r;
      omb[((size_t)(b * N_ + t)) * DIM_ + h * DH_ + d] = f2bf(o[j][r]);
    }
  }
}

extern "C" void kernel_launch(void* const* d_in, const int* in_sizes, int n_in,
                              void* d_out, int out_size, void* d_ws, size_t ws_size,
                              hipStream_t stream) {
  (void)in_sizes; (void)n_in; (void)out_size;
  const float* x = (const float*)d_in[0];
  const float* gamma = (const float*)d_in[1];
  const float* beta = (const float*)d_in[2];
  const float* wqkv = (const float*)d_in[3];
  const float* wout = (const float*)d_in[4];
  const float* bout = (const float*)d_in[5];
  const float* rk = (const float*)d_in[6];
  float* y = (float*)d_out;
  float* ws = (float*)d_ws;

  size_t o = 0;
  short* xnb = (short*)(ws + o);   o += (size_t)2 * N_ * DIM_ / 2;
  short* wqkvt = (short*)(ws + o); o += (size_t)3 * DIM_ * DIM_ / 2;
  short* woutt = (short*)(ws + o); o += (size_t)DIM_ * DIM_ / 2;
  short* qb = (short*)(ws + o);    o += (size_t)BH_ * N_ * DH_ / 2;
  short* kb = (short*)(ws + o);    o += (size_t)BH_ * N_ * DH_ / 2;
  short* vb = (short*)(ws + o);    o += (size_t)BH_ * N_ * DH_ / 2;
  short* vtb = (short*)(ws + o);   o += (size_t)BH_ * N_ * DH_ / 2;
  float* ql = ws + o;  o += (size_t)BH_ * M_ * DH_;
  float* kl = ws + o;  o += (size_t)BH_ * M_ * DH_;
  short* qlb = (short*)(ws + o); o += (size_t)BH_ * M_ * DH_ / 2;
  short* klb = (short*)(ws + o); o += (size_t)BH_ * M_ * DH_ / 2;
  float* a2 = ws + o;  o += (size_t)BH_ * M_ * M_;
  float* z0f = ws + o; o += (size_t)BH_ * M_ * M_;
  short* a2b = (short*)(ws + o); o += (size_t)BH_ * M_ * M_ / 2;
  short* zb0 = (short*)(ws + o); o += (size_t)BH_ * M_ * M_ / 2;
  short* zb1 = (short*)(ws + o); o += (size_t)BH_ * M_ * M_ / 2;
  short* yb0 = (short*)(ws + o); o += (size_t)BH_ * M_ * M_ / 2;
  short* yb1 = (short*)(ws + o); o += (size_t)BH_ * M_ * M_ / 2;
  short* p1b = (short*)(ws + o); o += (size_t)BH_ * M_ * M_ / 2;
  short* y2b = (short*)(ws + o); o += (size_t)BH_ * M_ * M_ / 2;
  short* wb  = (short*)(ws + o); o += (size_t)BH_ * M_ * M_ / 2;
  float* Opart = ws + o; o += (size_t)CH_ * 64 * 4096;
  float* mpart = ws + o; o += (size_t)CH_ * 64 * 64;
  float* lpart = ws + o; o += (size_t)CH_ * 64 * 64;
  float* a3v = ws + o; o += (size_t)BH_ * M_ * DH_;
  short* w2tb = (short*)(ws + o); o += (size_t)BH_ * M_ * DH_ / 2;
  short* omb = (short*)(ws + o);  o += (size_t)2 * N_ * DIM_ / 2;
  unsigned int* scalebits = (unsigned int*)(ws + o); o += 16;
  if (ws_size < o * sizeof(float)) return;

  (void)hipMemsetAsync(scalebits, 0, 64, stream);
  ln_kernel<<<2 * N_ / 4, 256, 0, stream>>>(x, gamma, beta, xnb);
  convt_kernel<<<dim3(3 * DIM_ / 32, DIM_ / 32), 256, 0, stream>>>(wqkv, wqkvt, DIM_, 3 * DIM_);
  convt_kernel<<<dim3(DIM_ / 32, DIM_ / 32), 256, 0, stream>>>(wout, woutt, DIM_, DIM_);
  qkv_mfma<<<dim3(2 * N_ / 128, 3 * DIM_ / 128), 256, 0, stream>>>(xnb, wqkvt, qb, kb, vb);
  vt_kernel<<<dim3(N_ / 32, 2, BH_), 256, 0, stream>>>(vb, vtb);

  landmark_kernel<<<BH_ * M_ * DH_ / 256, 256, 0, stream>>>(qb, kb, ql, kl, qlb, klb);
  sim2_softmax<<<dim3(M_, BH_), 256, 0, stream>>>(ql, kl, a2, a2b);
  colmax_kernel<<<BH_, 256, 0, stream>>>(a2, scalebits);
  transpose_scale<<<BH_ * M_ * M_ / 256, 256, 0, stream>>>(a2, zb0, scalebits);

  // a3 flash (independent of pinv)
  a3_flash<<<dim3(CH_, 4, BH_), 256, 0, stream>>>(qlb, kb, vtb, Opart, mpart, lpart);
  a3_combine<<<dim3(64, 4), 256, 0, stream>>>(Opart, mpart, lpart, a3v);

  // Newton-Schulz, 2 dependent launches/iter (kernel boundaries are the cheap
  // grid barrier on MI355X — cooperative grid.sync measured ~120 us/sync, R9)
  ns_gemm0<<<dim3(16, BH_), 256, 0, stream>>>(a2b, zb0, yb0);
  short* zc = zb0; short* zn = zb1; short* yc = yb0; short* yn = yb1;
  for (int it = 0; it < 6; ++it) {
    const int last = (it == 5);
    ns_stageA<<<dim3(16, 2 * BH_), 256, 0, stream>>>(zc, yc, p1b, y2b, wb);
    ns_stageB<<<dim3(16, last ? BH_ : 2 * BH_), 256, 0, stream>>>(
        p1b, y2b, wb, zc, yc, zn, yn, last ? z0f : nullptr, last);
    short* t;
    t = zc; zc = zn; zn = t;
    t = yc; yc = yn; yn = t;
  }

  // w2tb = bf16((z @ a3v)^T)  (w2t fused into epilogue)
  gemm_nn64<<<dim3(M_ / 64, 1, BH_), 256, 0, stream>>>(
      z0f, M_, (long long)M_ * M_, a3v, (long long)M_ * DH_, w2tb, M_);

  // fused a1 @ w2 + band-MFMA depthwise conv -> omb bf16
  a1_conv<<<dim3(N_ / 64, BH_), 256, 0, stream>>>(qb, klb, w2tb, vtb, rk, omb);

  final_mfma<<<dim3(2 * N_ / 128, DIM_ / 128), 256, 0, stream>>>(omb, woutt, x, bout, y);
}